// Round 1
// 612.646 us; speedup vs baseline: 1.1036x; 1.1036x over previous
//
#include <hip/hip_runtime.h>

// Problem constants
#define T_TOK 1024
#define HID   1024
#define NE    64
#define TOPKK 8
#define ITR   768
#define CAP   256

typedef __attribute__((ext_vector_type(4))) float f32x4;
typedef __attribute__((ext_vector_type(8))) short s16x8;

// ---- workspace layout (bytes) ----
// counts @0 (256B) | topki @1024 (32KB) | slot_of (32KB) | topkw (32KB) | etok (64KB)
// Xd bf16 [NE][CAP][HID] @256KiB (33.5MB)  | G bf16 [NE][CAP][ITR] (25.2MB)
// Y bf16 [NE][CAP][HID] aliases Xd (Xd dead after gemm1)
#define OFF_COUNTS 0
#define OFF_TOPKI  1024
#define OFF_SLOT   (OFF_TOPKI + T_TOK*TOPKK*4)
#define OFF_TOPKW  (OFF_SLOT  + T_TOK*TOPKK*4)
#define OFF_ETOK   (OFF_TOPKW + T_TOK*TOPKK*4)
#define OFF_XD     (1 << 18)
#define OFF_G      (OFF_XD + (size_t)NE*CAP*HID*2)
#define OFF_Y      OFF_XD

__device__ __forceinline__ unsigned short f2bf(float f) {
  union { float f; unsigned u; } v; v.f = f;
  unsigned r = v.u + 0x7FFFu + ((v.u >> 16) & 1u);   // RNE
  return (unsigned short)(r >> 16);
}
__device__ __forceinline__ float bf2f(unsigned short h) {
  union { unsigned u; float f; } v; v.u = ((unsigned)h) << 16;
  return v.f;
}
__device__ __forceinline__ unsigned pack2(float a, float b) {
  return (unsigned)f2bf(a) | ((unsigned)f2bf(b) << 16);
}

// async global->LDS, 16B per lane. LDS dest must be wave-uniform base + lane*16
// (our dest index is linear in tid, so this holds). Global source is per-lane,
// which is where the XOR swizzle is applied (rule: linear dest + pre-swizzled src).
__device__ __forceinline__ void gld_lds16(const unsigned short* g, unsigned short* l) {
  __builtin_amdgcn_global_load_lds(
      (const __attribute__((address_space(1))) unsigned int*)g,
      (__attribute__((address_space(3))) unsigned int*)l, 16, 0, 0);
}

// ---------------- router: fp64 logits -> softmax -> top8 -> renorm ----------------
__global__ __launch_bounds__(256) void router_k(
    const float* __restrict__ x, const float* __restrict__ gw,
    int* __restrict__ topki, float* __restrict__ topkw, int* __restrict__ counts)
{
  int t = blockIdx.x, tid = threadIdx.x;
  if (t == 0 && tid < NE) counts[tid] = 0;   // zero before assign_k (next kernel)
  __shared__ float xs[HID];
  __shared__ double parts[4 * 64];
  *(f32x4*)&xs[tid * 4] = *(const f32x4*)(x + (size_t)t * HID + tid * 4);
  __syncthreads();
  int e = tid & 63, part = tid >> 6;
  const float* g  = gw + (size_t)e * HID + part * 256;
  const float* xp = xs + part * 256;
  double acc = 0.0;
  #pragma unroll 4
  for (int h = 0; h < 256; h += 4) {
    f32x4 gv = *(const f32x4*)(g + h);
    f32x4 xv = *(const f32x4*)(xp + h);
    acc += (double)xv.x * gv.x + (double)xv.y * gv.y
         + (double)xv.z * gv.z + (double)xv.w * gv.w;
  }
  parts[part * 64 + e] = acc;
  __syncthreads();
  if (tid < 64) {
    double l = parts[tid] + parts[64 + tid] + parts[128 + tid] + parts[192 + tid];
    double m = l;
    for (int off = 32; off >= 1; off >>= 1) {
      double o = __shfl_xor(m, off, 64);
      m = o > m ? o : m;
    }
    double p  = exp(l - m);   // softmax normalizer cancels in top-8 renorm
    double pv = p;
    double wv[TOPKK]; int wi[TOPKK];
    double sum8 = 0.0;
    #pragma unroll
    for (int j = 0; j < TOPKK; ++j) {
      double bv = pv; int bi = tid;
      for (int off = 32; off >= 1; off >>= 1) {
        double ov = __shfl_xor(bv, off, 64);
        int    oi = __shfl_xor(bi, off, 64);
        if (ov > bv || (ov == bv && oi < bi)) { bv = ov; bi = oi; }  // lax.top_k tiebreak
      }
      wv[j] = bv; wi[j] = bi; sum8 += bv;
      if (tid == bi) pv = -1.0;
    }
    if (tid == 0) {
      double inv = 1.0 / sum8;
      #pragma unroll
      for (int j = 0; j < TOPKK; ++j) {
        topki[t * TOPKK + j] = wi[j];
        topkw[t * TOPKK + j] = (float)(wv[j] * inv);
      }
    }
  }
}

// ---------------- slot assignment (atomic; permutation is arithmetically inert) ----
__global__ __launch_bounds__(256) void assign_k(
    const int* __restrict__ topki, int* __restrict__ counts,
    int* __restrict__ slot_of, int* __restrict__ etok)
{
  int a = blockIdx.x * 256 + threadIdx.x;
  if (a >= T_TOK * TOPKK) return;
  int e = topki[a];
  int s = atomicAdd(counts + e, 1);
  if (s < CAP) { slot_of[a] = s; etok[e * CAP + s] = a >> 3; }
  else         { slot_of[a] = -1; }
}

// ---------------- gather token rows into per-expert bf16 buffer ----------------
__global__ __launch_bounds__(128) void dispatch_k(
    const float* __restrict__ x, const int* __restrict__ counts,
    const int* __restrict__ etok, unsigned short* __restrict__ Xd)
{
  int b = blockIdx.x;
  int e = b >> 8, s = b & 255;
  int cnt = min(counts[e], CAP);
  if (s >= cnt) return;
  int t = etok[b];
  const float* src = x + (size_t)t * HID;
  unsigned short* dst = Xd + (size_t)b * HID;
  int tid = threadIdx.x;
  #pragma unroll
  for (int i = 0; i < 2; ++i) {
    int h = (tid + i * 128) * 4;
    f32x4 v = *(const f32x4*)(src + h);
    ushort4 o;
    o.x = f2bf(v.x); o.y = f2bf(v.y); o.z = f2bf(v.z); o.w = f2bf(v.w);
    *(ushort4*)(dst + h) = o;
  }
}

// ---------------- GEMM1: G = silu(Xd Wg^T) * (Xd Wu^T), bf16 MFMA ----------------
// One block per (expert, 64-col tile): 256 capacity rows x 64 cols, BK=64.
// Weights (HBM-bound part) are read EXACTLY ONCE. A (bf16, L3-resident) goes
// through global_load_lds with XOR seg-swizzle on the source address; B (fp32)
// is reg-prefetched one K-step ahead (drained by the next barrier's vmcnt(0)),
// converted to bf16 and ds_written with the same swizzle.
// LDS swizzle convention: LDS(row, seg) = Global(row, seg ^ (row & 7)),
// segs are 16B; frag read addr = row*64 + ((t ^ (row&7)) * 8) shorts.
__global__ __launch_bounds__(256, 2) void gemm1_k(
    const unsigned short* __restrict__ Xd, const float* __restrict__ wg,
    const float* __restrict__ wu, const int* __restrict__ counts,
    unsigned short* __restrict__ G)
{
  int bx = blockIdx.x;
  int ct = bx % 12;
  int e  = bx / 12;
  int cnt = min(counts[e], CAP);
  if (cnt <= 0) return;
  int ru = (cnt + 63) & ~63;        // rows to stage/compute (rounded to wave tile)

  __shared__ unsigned short As[CAP * 64];   // 32KB, xor-swizzled, via global_load_lds
  __shared__ unsigned short Bg[64 * 64];    // 8KB
  __shared__ unsigned short Bu[64 * 64];    // 8KB

  int tid = threadIdx.x;
  int lane = tid & 63, w = tid >> 6;        // wave w owns rows [w*64, w*64+64)
  bool wactive = (w * 64) < ru;

  const unsigned short* Abase = Xd + (size_t)e * CAP * HID;
  const float* gbase = wg + ((size_t)e * ITR + ct * 64) * HID;
  const float* ubase = wu + ((size_t)e * ITR + ct * 64) * HID;

  int br = tid >> 3;                // B row 0..31 (+j*32)
  int bs = tid & 7;                 // B source seg

  // prologue: prefetch B for kc=0
  f32x4 pg[2][2], pu[2][2];
  #pragma unroll
  for (int j = 0; j < 2; ++j) {
    const float* p0 = gbase + (size_t)(br + j * 32) * HID + bs * 8;
    pg[j][0] = *(const f32x4*)p0;  pg[j][1] = *(const f32x4*)(p0 + 4);
    const float* p1 = ubase + (size_t)(br + j * 32) * HID + bs * 8;
    pu[j][0] = *(const f32x4*)p1;  pu[j][1] = *(const f32x4*)(p1 + 4);
  }

  f32x4 accg[4][4], accu[4][4];
  #pragma unroll
  for (int i = 0; i < 4; ++i)
    #pragma unroll
    for (int j = 0; j < 4; ++j) { accg[i][j] = (f32x4)0.0f; accu[i][j] = (f32x4)0.0f; }

  for (int kc = 0; kc < HID / 64; ++kc) {
    int k0 = kc * 64;
    __syncthreads();   // prev-step LDS reads done; drains this step's prefetched B loads
    // A -> LDS (direct DMA; source seg pre-swizzled, dest linear)
    #pragma unroll
    for (int i = 0; i < 8; ++i) {
      if (i * 32 < ru) {
        int q = tid + i * 256;
        int r = q >> 3, s = q & 7;
        int ss = s ^ (r & 7);
        gld_lds16(Abase + (size_t)r * HID + k0 + ss * 8, &As[q * 8]);
      }
    }
    // B: convert prefetched fp32 -> bf16, swizzled ds_write
    #pragma unroll
    for (int j = 0; j < 2; ++j) {
      int r = br + j * 32;
      int sw = bs ^ (r & 7);
      uint4 pk;
      pk.x = pack2(pg[j][0].x, pg[j][0].y); pk.y = pack2(pg[j][0].z, pg[j][0].w);
      pk.z = pack2(pg[j][1].x, pg[j][1].y); pk.w = pack2(pg[j][1].z, pg[j][1].w);
      *(uint4*)&Bg[r * 64 + sw * 8] = pk;
      pk.x = pack2(pu[j][0].x, pu[j][0].y); pk.y = pack2(pu[j][0].z, pu[j][0].w);
      pk.z = pack2(pu[j][1].x, pu[j][1].y); pk.w = pack2(pu[j][1].z, pu[j][1].w);
      *(uint4*)&Bu[r * 64 + sw * 8] = pk;
    }
    __syncthreads();   // drains A DMA (vmcnt0) + B ds_writes (lgkm)
    // prefetch next K-step's B: in flight across the whole MFMA phase
    if (kc + 1 < HID / 64) {
      int k1 = k0 + 64;
      #pragma unroll
      for (int j = 0; j < 2; ++j) {
        const float* p0 = gbase + (size_t)(br + j * 32) * HID + k1 + bs * 8;
        pg[j][0] = *(const f32x4*)p0;  pg[j][1] = *(const f32x4*)(p0 + 4);
        const float* p1 = ubase + (size_t)(br + j * 32) * HID + k1 + bs * 8;
        pu[j][0] = *(const f32x4*)p1;  pu[j][1] = *(const f32x4*)(p1 + 4);
      }
    }
    if (wactive) {
      #pragma unroll
      for (int ks = 0; ks < 2; ++ks) {
        int t = ks * 4 + (lane >> 4);
        s16x8 af[4];
        #pragma unroll
        for (int mt = 0; mt < 4; ++mt) {
          int R = w * 64 + mt * 16 + (lane & 15);
          af[mt] = *(const s16x8*)&As[R * 64 + (t ^ (R & 7)) * 8];
        }
        #pragma unroll
        for (int nt = 0; nt < 4; ++nt) {
          int rB = nt * 16 + (lane & 15);
          int sB = (t ^ (rB & 7)) * 8;
          s16x8 bg = *(const s16x8*)&Bg[rB * 64 + sB];
          s16x8 bu = *(const s16x8*)&Bu[rB * 64 + sB];
          #pragma unroll
          for (int mt = 0; mt < 4; ++mt) {
            accg[mt][nt] = __builtin_amdgcn_mfma_f32_16x16x32_bf16(af[mt], bg, accg[mt][nt], 0, 0, 0);
            accu[mt][nt] = __builtin_amdgcn_mfma_f32_16x16x32_bf16(af[mt], bu, accu[mt][nt], 0, 0, 0);
          }
        }
      }
    }
  }
  // epilogue: silu(g)*u -> bf16  (C/D map: col=lane&15, row=(lane>>4)*4+reg)
  if (wactive) {
    unsigned short* Gout = G + (size_t)e * CAP * ITR;
    #pragma unroll
    for (int mt = 0; mt < 4; ++mt)
      #pragma unroll
      for (int nt = 0; nt < 4; ++nt)
        #pragma unroll
        for (int r = 0; r < 4; ++r) {
          int row = w * 64 + mt * 16 + (lane >> 4) * 4 + r;
          int col = ct * 64 + nt * 16 + (lane & 15);
          float gv = accg[mt][nt][r];
          float uv = accu[mt][nt][r];
          float sg = gv / (1.0f + __expf(-gv));
          Gout[(size_t)row * ITR + col] = f2bf(sg * uv);
        }
  }
}

// ---------------- GEMM2: Y = G Wd^T (same structure, single B matrix) ----------------
__global__ __launch_bounds__(256, 3) void gemm2_k(
    const unsigned short* __restrict__ G, const float* __restrict__ wd,
    const int* __restrict__ counts, unsigned short* __restrict__ Y)
{
  int bx = blockIdx.x;
  int ct = bx & 15;
  int e  = bx >> 4;
  int cnt = min(counts[e], CAP);
  if (cnt <= 0) return;
  int ru = (cnt + 63) & ~63;

  __shared__ unsigned short As[CAP * 64];   // 32KB
  __shared__ unsigned short Bs[64 * 64];    // 8KB

  int tid = threadIdx.x;
  int lane = tid & 63, w = tid >> 6;
  bool wactive = (w * 64) < ru;

  const unsigned short* Abase = G + (size_t)e * CAP * ITR;
  const float* bbase = wd + ((size_t)e * HID + ct * 64) * ITR;

  int br = tid >> 3, bs = tid & 7;

  f32x4 pb[2][2];
  #pragma unroll
  for (int j = 0; j < 2; ++j) {
    const float* p0 = bbase + (size_t)(br + j * 32) * ITR + bs * 8;
    pb[j][0] = *(const f32x4*)p0;  pb[j][1] = *(const f32x4*)(p0 + 4);
  }

  f32x4 acc[4][4];
  #pragma unroll
  for (int i = 0; i < 4; ++i)
    #pragma unroll
    for (int j = 0; j < 4; ++j) acc[i][j] = (f32x4)0.0f;

  for (int kc = 0; kc < ITR / 64; ++kc) {
    int k0 = kc * 64;
    __syncthreads();
    #pragma unroll
    for (int i = 0; i < 8; ++i) {
      if (i * 32 < ru) {
        int q = tid + i * 256;
        int r = q >> 3, s = q & 7;
        int ss = s ^ (r & 7);
        gld_lds16(Abase + (size_t)r * ITR + k0 + ss * 8, &As[q * 8]);
      }
    }
    #pragma unroll
    for (int j = 0; j < 2; ++j) {
      int r = br + j * 32;
      int sw = bs ^ (r & 7);
      uint4 pk;
      pk.x = pack2(pb[j][0].x, pb[j][0].y); pk.y = pack2(pb[j][0].z, pb[j][0].w);
      pk.z = pack2(pb[j][1].x, pb[j][1].y); pk.w = pack2(pb[j][1].z, pb[j][1].w);
      *(uint4*)&Bs[r * 64 + sw * 8] = pk;
    }
    __syncthreads();
    if (kc + 1 < ITR / 64) {
      int k1 = k0 + 64;
      #pragma unroll
      for (int j = 0; j < 2; ++j) {
        const float* p0 = bbase + (size_t)(br + j * 32) * ITR + k1 + bs * 8;
        pb[j][0] = *(const f32x4*)p0;  pb[j][1] = *(const f32x4*)(p0 + 4);
      }
    }
    if (wactive) {
      #pragma unroll
      for (int ks = 0; ks < 2; ++ks) {
        int t = ks * 4 + (lane >> 4);
        s16x8 af[4];
        #pragma unroll
        for (int mt = 0; mt < 4; ++mt) {
          int R = w * 64 + mt * 16 + (lane & 15);
          af[mt] = *(const s16x8*)&As[R * 64 + (t ^ (R & 7)) * 8];
        }
        #pragma unroll
        for (int nt = 0; nt < 4; ++nt) {
          int rB = nt * 16 + (lane & 15);
          s16x8 bf = *(const s16x8*)&Bs[rB * 64 + (t ^ (rB & 7)) * 8];
          #pragma unroll
          for (int mt = 0; mt < 4; ++mt)
            acc[mt][nt] = __builtin_amdgcn_mfma_f32_16x16x32_bf16(af[mt], bf, acc[mt][nt], 0, 0, 0);
        }
      }
    }
  }
  if (wactive) {
    unsigned short* Yout = Y + (size_t)e * CAP * HID;
    #pragma unroll
    for (int mt = 0; mt < 4; ++mt)
      #pragma unroll
      for (int nt = 0; nt < 4; ++nt)
        #pragma unroll
        for (int r = 0; r < 4; ++r) {
          int row = w * 64 + mt * 16 + (lane >> 4) * 4 + r;
          int col = ct * 64 + nt * 16 + (lane & 15);
          Yout[(size_t)row * HID + col] = f2bf(acc[mt][nt][r]);
        }
  }
}

// ---------------- combine: out[t] = sum_k w * Y[e_k, slot_k] ----------------
__global__ __launch_bounds__(256) void combine_k(
    const unsigned short* __restrict__ Y, const int* __restrict__ topki,
    const int* __restrict__ slot_of, const float* __restrict__ topkw,
    float* __restrict__ out)
{
  int t = blockIdx.x, tid = threadIdx.x;
  int h = tid * 4;
  float a0 = 0.f, a1 = 0.f, a2 = 0.f, a3 = 0.f;
  #pragma unroll
  for (int k = 0; k < TOPKK; ++k) {
    int a = t * TOPKK + k;
    int s = slot_of[a];
    if (s < 0) continue;
    int e = topki[a];
    float wt = topkw[a];
    const unsigned short* yp = Y + ((size_t)(e * CAP + s)) * HID + h;
    ushort4 yv = *(const ushort4*)yp;
    a0 += wt * bf2f(yv.x);
    a1 += wt * bf2f(yv.y);
    a2 += wt * bf2f(yv.z);
    a3 += wt * bf2f(yv.w);
  }
  f32x4 o = { a0, a1, a2, a3 };
  *(f32x4*)(out + (size_t)t * HID + h) = o;
}

extern "C" void kernel_launch(void* const* d_in, const int* in_sizes, int n_in,
                              void* d_out, int out_size, void* d_ws, size_t ws_size,
                              hipStream_t stream)
{
  const float* x     = (const float*)d_in[0];
  const float* gw    = (const float*)d_in[1];
  const float* wgate = (const float*)d_in[2];
  const float* wup   = (const float*)d_in[3];
  const float* wdown = (const float*)d_in[4];
  float* out = (float*)d_out;

  char* ws = (char*)d_ws;
  int*   counts  = (int*)  (ws + OFF_COUNTS);
  int*   topki   = (int*)  (ws + OFF_TOPKI);
  int*   slot_of = (int*)  (ws + OFF_SLOT);
  float* topkw   = (float*)(ws + OFF_TOPKW);
  int*   etok    = (int*)  (ws + OFF_ETOK);
  unsigned short* Xd = (unsigned short*)(ws + OFF_XD);
  unsigned short* G  = (unsigned short*)(ws + OFF_G);
  unsigned short* Y  = (unsigned short*)(ws + OFF_Y);  // aliases Xd (dead after gemm1)

  router_k  <<<T_TOK, 256, 0, stream>>>(x, gw, topki, topkw, counts);
  assign_k  <<<(T_TOK * TOPKK) / 256, 256, 0, stream>>>(topki, counts, slot_of, etok);
  dispatch_k<<<NE * CAP, 128, 0, stream>>>(x, counts, etok, Xd);
  gemm1_k   <<<NE * 12, 256, 0, stream>>>(Xd, wgate, wup, counts, G);
  gemm2_k   <<<NE * 16, 256, 0, stream>>>(G, wdown, counts, Y);
  combine_k <<<T_TOK, 256, 0, stream>>>(Y, topki, slot_of, topkw, out);
}